// Round 2
// baseline (1024.971 us; speedup 1.0000x reference)
//
#include <hip/hip_runtime.h>
#include <stdint.h>

// ---------------- problem constants (fixed by setup_inputs) ----------------
#define G       69
#define BATCH   8
// sparse_shape (Z,Y,X) = (32,512,512), window (12,12,32), SHIFT=true
// mwx = 44, mwy = 44, mwz = 2
#define MPS     3872        // 44*44*2
#define VOL     4608        // 12*12*32
// max key = 142,737,407 < 2^28
#define NBUK    1089        // buckets per map: key>>17; 1089*131072 = 142,737,408 exactly
#define NB2     2178        // both maps
#define B_WORDS 4096        // 2^17 bits per bucket / 32

// ctrl layout (int32 indices)
#define C_COUNTS 0   // [8]
#define C_BS     8   // [9]
#define C_CP     17  // [8]
#define C_BSP    25  // [9]

// ---------------- K1: fused batch + bucket histogram ----------------
__device__ __forceinline__ void keys_from_coord(int4 c, unsigned& kx, unsigned& ky) {
    int b  = c.x;
    int zz = c.y + 16;   // z + win_z/2
    int yy = c.z + 6;    // y + win_y/2
    int xx = c.w + 6;    // x + win_x/2
    int wx = xx / 12, cx = xx - wx*12;
    int wy = yy / 12, cy = yy - wy*12;
    int wz = zz >> 5, cz = zz & 31;
    int bwx = b*MPS + wx*88 + wy*2 + wz;   // mwy*mwz = 88
    int bwy = b*MPS + wy*88 + wx*2 + wz;   // mwx*mwz = 88
    kx = (unsigned)(bwx*VOL + cx*384 + cy*32 + cz);  // win_y*win_z = 384
    ky = (unsigned)(bwy*VOL + cy*384 + cx*32 + cz);  // win_x*win_z = 384
}

__global__ void hist_kernel(const int4* __restrict__ coords, int N,
                            int* __restrict__ ctrl, unsigned* __restrict__ hist) {
    __shared__ unsigned h[NB2];
    __shared__ int hb[BATCH];
    int t = threadIdx.x;
    for (int k = t; k < NB2; k += 256) h[k] = 0;
    if (t < BATCH) hb[t] = 0;
    __syncthreads();
    int c0=0,c1=0,c2=0,c3=0,c4=0,c5=0,c6=0,c7=0;
    for (int i = blockIdx.x*blockDim.x + t; i < N; i += gridDim.x*blockDim.x) {
        int4 c = coords[i];
        int b = c.x;
        c0 += (b==0); c1 += (b==1); c2 += (b==2); c3 += (b==3);
        c4 += (b==4); c5 += (b==5); c6 += (b==6); c7 += (b==7);
        unsigned kx, ky;
        keys_from_coord(c, kx, ky);
        atomicAdd(&h[kx >> 17], 1u);
        atomicAdd(&h[NBUK + (ky >> 17)], 1u);
    }
    atomicAdd(&hb[0],c0); atomicAdd(&hb[1],c1); atomicAdd(&hb[2],c2); atomicAdd(&hb[3],c3);
    atomicAdd(&hb[4],c4); atomicAdd(&hb[5],c5); atomicAdd(&hb[6],c6); atomicAdd(&hb[7],c7);
    __syncthreads();
    for (int k = t; k < NB2; k += 256)
        if (h[k]) atomicAdd(&hist[k], h[k]);
    if (t < BATCH && hb[t]) atomicAdd(&ctrl[C_COUNTS + t], hb[t]);
}

// ---------------- K2: batch prep + bucket-count exclusive scan ----------------
__global__ void scan_kernel(int* __restrict__ ctrl, const unsigned* __restrict__ hist,
                            unsigned* __restrict__ recStart, unsigned* __restrict__ cursor) {
    int t = threadIdx.x;
    if (t == 0) {
        int bs = 0, bsp = 0;
        ctrl[C_BS] = 0; ctrl[C_BSP] = 0;
        for (int b = 0; b < BATCH; b++) {
            int n  = ctrl[C_COUNTS + b];
            int np = ((n + G - 1) / G) * G;
            ctrl[C_CP + b] = np;
            bs += n; bsp += np;
            ctrl[C_BS + b + 1]  = bs;
            ctrl[C_BSP + b + 1] = bsp;
        }
    }
    __shared__ unsigned sc[256];
    __shared__ unsigned s_run;
    if (t == 0) s_run = 0;
    __syncthreads();
    for (int base = 0; base < NB2; base += 256) {
        unsigned v = (base + t < NB2) ? hist[base + t] : 0;
        sc[t] = v; __syncthreads();
        for (int d = 1; d < 256; d <<= 1) {
            unsigned u = (t >= d) ? sc[t - d] : 0;
            __syncthreads();
            sc[t] += u;
            __syncthreads();
        }
        unsigned excl = s_run + sc[t] - v;
        if (base + t < NB2) { recStart[base + t] = excl; cursor[base + t] = excl; }
        unsigned tot = sc[255];
        __syncthreads();
        if (t == 0) s_run += tot;
        __syncthreads();
    }
    if (t == 0) recStart[NB2] = s_run;   // == 2N
}

// ---------------- K3: scatter records to buckets + win2flat ----------------
__global__ void bin_kernel(const int4* __restrict__ coords, int N,
                           const int* __restrict__ ctrl,
                           unsigned* __restrict__ cursor,
                           uint2* __restrict__ rec,
                           int* __restrict__ win2flat) {
    __shared__ int s_off[BATCH];
    if (threadIdx.x < BATCH)
        s_off[threadIdx.x] = ctrl[C_BSP + threadIdx.x] - ctrl[C_BS + threadIdx.x];
    __syncthreads();
    int i = blockIdx.x*blockDim.x + threadIdx.x;
    if (i >= N) return;
    int4 c = coords[i];
    win2flat[i] = i + s_off[c.x];
    unsigned kx, ky;
    keys_from_coord(c, kx, ky);
    unsigned px = atomicAdd(&cursor[kx >> 17], 1u);
    rec[px] = make_uint2(kx, (unsigned)i);
    unsigned py = atomicAdd(&cursor[NBUK + (ky >> 17)], 1u);
    rec[py] = make_uint2(ky, (unsigned)i);
}

// ---------------- K4: flat2win (closed form over padded index space) ----------------
__global__ void f2w_kernel(int Np, const int* __restrict__ ctrl, int* __restrict__ out) {
    __shared__ int s_bs[BATCH+1], s_bsp[BATCH+1], s_cnt[BATCH], s_cp[BATCH];
    int t = threadIdx.x;
    if (t < BATCH)   { s_cnt[t] = ctrl[C_COUNTS+t]; s_cp[t] = ctrl[C_CP+t]; }
    if (t < BATCH+1) { s_bs[t]  = ctrl[C_BS+t];     s_bsp[t] = ctrl[C_BSP+t]; }
    __syncthreads();
    int j = blockIdx.x*blockDim.x + t;
    if (j >= Np) return;
    int b = 0;
    #pragma unroll
    for (int k = 1; k < BATCH; k++) b += (j >= s_bsp[k]);
    int off  = s_bsp[b] - s_bs[b];
    int num  = s_cnt[b], nump = s_cp[b];
    int r    = num % G;
    int tail_start = (num != nump) ? (s_bsp[b+1] - G + r) : s_bsp[b+1];
    int v;
    if (j < tail_start)       v = j - off;
    else if (nump != G)       v = j - G - off;
    else { int tt = j - tail_start; int m = num > 0 ? num : 1; v = s_bs[b] + tt % m; }
    out[j] = v;
}

// ---------------- K5: per-bucket LDS bitmap rank + scatter ----------------
__global__ void rank_kernel(const uint2* __restrict__ rec,
                            const unsigned* __restrict__ recStart, int N,
                            int* __restrict__ xmap, int* __restrict__ ymap) {
    int b = blockIdx.x;                      // 0..NB2-1
    unsigned start = recStart[b], end = recStart[b+1];
    int map = (b >= NBUK);
    __shared__ unsigned bits[B_WORDS];
    __shared__ unsigned pref[B_WORDS];
    __shared__ unsigned sc[256];
    int t = threadIdx.x;
    #pragma unroll
    for (int k = 0; k < B_WORDS/256; k++) bits[t + 256*k] = 0;
    __syncthreads();
    for (unsigned i = start + t; i < end; i += 256) {
        unsigned key = rec[i].x;
        unsigned local = key & 131071u;
        atomicOr(&bits[local >> 5], 1u << (local & 31));
    }
    __syncthreads();
    // per-thread 16 consecutive words -> popcount block scan
    unsigned base = t * 16;
    unsigned w[16];
    unsigned s = 0;
    #pragma unroll
    for (int k = 0; k < 16; k++) { w[k] = bits[base + k]; s += __popc(w[k]); }
    sc[t] = s; __syncthreads();
    for (int d = 1; d < 256; d <<= 1) {
        unsigned u = (t >= d) ? sc[t - d] : 0;
        __syncthreads();
        sc[t] += u;
        __syncthreads();
    }
    unsigned excl = sc[t] - s;
    #pragma unroll
    for (int k = 0; k < 16; k++) { pref[base + k] = excl; excl += __popc(w[k]); }
    __syncthreads();
    int* out = map ? ymap : xmap;
    unsigned rankBase = start - (map ? (unsigned)N : 0u);
    for (unsigned i = start + t; i < end; i += 256) {
        uint2 r = rec[i];
        unsigned local = r.x & 131071u;
        unsigned wd = local >> 5, bt = local & 31;
        unsigned rank = rankBase + pref[wd] + __popc(bits[wd] & ((1u << bt) - 1u));
        out[rank] = (int)r.y;
    }
}

// ---------------- launch ----------------
extern "C" void kernel_launch(void* const* d_in, const int* in_sizes, int n_in,
                              void* d_out, int out_size, void* d_ws, size_t ws_size,
                              hipStream_t stream) {
    const int* coords = (const int*)d_in[0];
    int N  = in_sizes[0] / 4;
    int Np = out_size - 3 * N;

    char* ws = (char*)d_ws;
    int*      ctrl     = (int*)(ws + 0);            // 256 B
    unsigned* hist     = (unsigned*)(ws + 256);     // 2178*4 = 8712 B  -> ends 8968
    unsigned* recStart = (unsigned*)(ws + 8968);    // 2179*4 = 8716 B  -> ends 17684
    unsigned* cursor   = (unsigned*)(ws + 17684);   // 2178*4 = 8712 B  -> ends 26396
    uint2*    rec      = (uint2*)(ws + 26400);      // 2N*8 B (~32 MB)

    int* out  = (int*)d_out;
    int* f2w  = out;
    int* w2f  = out + Np;
    int* xmap = out + Np + N;
    int* ymap = out + Np + 2*N;

    hipMemsetAsync(ws, 0, 8968, stream);   // ctrl + hist

    hist_kernel<<<512, 256, 0, stream>>>((const int4*)coords, N, ctrl, hist);
    scan_kernel<<<1, 256, 0, stream>>>(ctrl, hist, recStart, cursor);
    bin_kernel<<<(N + 255)/256, 256, 0, stream>>>((const int4*)coords, N, ctrl, cursor, rec, w2f);
    f2w_kernel<<<(Np + 255)/256, 256, 0, stream>>>(Np, ctrl, f2w);
    rank_kernel<<<NB2, 256, 0, stream>>>(rec, recStart, N, xmap, ymap);
}

// Round 3
// 185.552 us; speedup vs baseline: 5.5239x; 5.5239x over previous
//
#include <hip/hip_runtime.h>
#include <stdint.h>

// ---------------- problem constants (fixed by setup_inputs) ----------------
#define G       69
#define BATCH   8
// sparse_shape (Z,Y,X) = (32,512,512), window (12,12,32), SHIFT=true
// mwx = 44, mwy = 44, mwz = 2
#define MPS     3872        // 44*44*2
#define VOL     4608        // 12*12*32
// max key = 142,737,407 < 2^28
#define NBUK    1089        // buckets per map: key>>17; 1089*131072 = 142,737,408 exactly
#define NB2     2178        // both maps
#define B_WORDS 4096        // 2^17 bits per bucket / 32
#define NBLK    256         // chunks for the counting sort

// ctrl layout (int32 indices)
#define C_COUNTS 0   // [8]
#define C_BS     8   // [9]
#define C_CP     17  // [8]
#define C_BSP    25  // [9]

__device__ __forceinline__ void keys_from_coord(int4 c, unsigned& kx, unsigned& ky) {
    int b  = c.x;
    int zz = c.y + 16;   // z + win_z/2
    int yy = c.z + 6;    // y + win_y/2
    int xx = c.w + 6;    // x + win_x/2
    int wx = xx / 12, cx = xx - wx*12;
    int wy = yy / 12, cy = yy - wy*12;
    int wz = zz >> 5, cz = zz & 31;
    int bwx = b*MPS + wx*88 + wy*2 + wz;   // mwy*mwz = 88
    int bwy = b*MPS + wy*88 + wx*2 + wz;   // mwx*mwz = 88
    kx = (unsigned)(bwx*VOL + cx*384 + cy*32 + cz);  // win_y*win_z = 384
    ky = (unsigned)(bwy*VOL + cy*384 + cx*32 + cz);  // win_x*win_z = 384
}

// ---------------- K1: per-chunk LDS bucket histogram + batch counts ----------------
__global__ void hist_kernel(const int4* __restrict__ coords, int N, int chunk,
                            int* __restrict__ ctrl, unsigned* __restrict__ histMat) {
    __shared__ unsigned h[NB2];
    __shared__ int hb[BATCH];
    int t = threadIdx.x, blk = blockIdx.x;
    for (int k = t; k < NB2; k += 256) h[k] = 0;
    if (t < BATCH) hb[t] = 0;
    __syncthreads();
    int start = blk * chunk;
    int end   = min(start + chunk, N);
    int c0=0,c1=0,c2=0,c3=0,c4=0,c5=0,c6=0,c7=0;
    for (int i = start + t; i < end; i += 256) {
        int4 c = coords[i];
        int b = c.x;
        c0 += (b==0); c1 += (b==1); c2 += (b==2); c3 += (b==3);
        c4 += (b==4); c5 += (b==5); c6 += (b==6); c7 += (b==7);
        unsigned kx, ky;
        keys_from_coord(c, kx, ky);
        atomicAdd(&h[kx >> 17], 1u);
        atomicAdd(&h[NBUK + (ky >> 17)], 1u);
    }
    atomicAdd(&hb[0],c0); atomicAdd(&hb[1],c1); atomicAdd(&hb[2],c2); atomicAdd(&hb[3],c3);
    atomicAdd(&hb[4],c4); atomicAdd(&hb[5],c5); atomicAdd(&hb[6],c6); atomicAdd(&hb[7],c7);
    __syncthreads();
    // coalesced row write
    for (int k = t; k < NB2; k += 256) histMat[(size_t)blk * NB2 + k] = h[k];
    if (t < BATCH && hb[t]) atomicAdd(&ctrl[C_COUNTS + t], hb[t]);
}

// ---------------- K2a: per-bucket column exclusive scan over blocks ----------------
__global__ void colscan_kernel(unsigned* __restrict__ histMat, unsigned* __restrict__ totals) {
    int k = blockIdx.x * blockDim.x + threadIdx.x;
    if (k >= NB2) return;
    unsigned run = 0;
    for (int b = 0; b < NBLK; b++) {
        unsigned v = histMat[(size_t)b * NB2 + k];
        histMat[(size_t)b * NB2 + k] = run;
        run += v;
    }
    totals[k] = run;
}

// ---------------- K2b: bucket-total scan -> recStart; batch prefix prep ----------------
__global__ void scan_kernel(int* __restrict__ ctrl, const unsigned* __restrict__ totals,
                            unsigned* __restrict__ recStart) {
    int t = threadIdx.x;
    if (t == 0) {
        int bs = 0, bsp = 0;
        ctrl[C_BS] = 0; ctrl[C_BSP] = 0;
        for (int b = 0; b < BATCH; b++) {
            int n  = ctrl[C_COUNTS + b];
            int np = ((n + G - 1) / G) * G;
            ctrl[C_CP + b] = np;
            bs += n; bsp += np;
            ctrl[C_BS + b + 1]  = bs;
            ctrl[C_BSP + b + 1] = bsp;
        }
    }
    __shared__ unsigned sc[256];
    __shared__ unsigned s_run;
    if (t == 0) s_run = 0;
    __syncthreads();
    for (int base = 0; base < NB2; base += 256) {
        unsigned v = (base + t < NB2) ? totals[base + t] : 0;
        sc[t] = v; __syncthreads();
        for (int d = 1; d < 256; d <<= 1) {
            unsigned u = (t >= d) ? sc[t - d] : 0;
            __syncthreads();
            sc[t] += u;
            __syncthreads();
        }
        unsigned excl = s_run + sc[t] - v;
        if (base + t < NB2) recStart[base + t] = excl;
        unsigned tot = sc[255];
        __syncthreads();
        if (t == 0) s_run += tot;
        __syncthreads();
    }
    if (t == 0) recStart[NB2] = s_run;   // == 2N
}

// ---------------- K3: contention-free binning via LDS cursors + win2flat ----------------
__global__ void bin_kernel(const int4* __restrict__ coords, int N, int chunk,
                           const int* __restrict__ ctrl,
                           const unsigned* __restrict__ recStart,
                           const unsigned* __restrict__ histMat,
                           uint2* __restrict__ rec,
                           int* __restrict__ win2flat) {
    __shared__ unsigned cur[NB2];
    __shared__ int s_off[BATCH];
    int t = threadIdx.x, blk = blockIdx.x;
    if (t < BATCH)
        s_off[t] = ctrl[C_BSP + t] - ctrl[C_BS + t];
    for (int k = t; k < NB2; k += 256)
        cur[k] = recStart[k] + histMat[(size_t)blk * NB2 + k];
    __syncthreads();
    int start = blk * chunk;
    int end   = min(start + chunk, N);
    for (int i = start + t; i < end; i += 256) {
        int4 c = coords[i];
        win2flat[i] = i + s_off[c.x];
        unsigned kx, ky;
        keys_from_coord(c, kx, ky);
        unsigned px = atomicAdd(&cur[kx >> 17], 1u);
        rec[px] = make_uint2(kx, (unsigned)i);
        unsigned py = atomicAdd(&cur[NBUK + (ky >> 17)], 1u);
        rec[py] = make_uint2(ky, (unsigned)i);
    }
}

// ---------------- K4: flat2win (closed form over padded index space) ----------------
__global__ void f2w_kernel(int Np, const int* __restrict__ ctrl, int* __restrict__ out) {
    __shared__ int s_bs[BATCH+1], s_bsp[BATCH+1], s_cnt[BATCH], s_cp[BATCH];
    int t = threadIdx.x;
    if (t < BATCH)   { s_cnt[t] = ctrl[C_COUNTS+t]; s_cp[t] = ctrl[C_CP+t]; }
    if (t < BATCH+1) { s_bs[t]  = ctrl[C_BS+t];     s_bsp[t] = ctrl[C_BSP+t]; }
    __syncthreads();
    int j = blockIdx.x*blockDim.x + t;
    if (j >= Np) return;
    int b = 0;
    #pragma unroll
    for (int k = 1; k < BATCH; k++) b += (j >= s_bsp[k]);
    int off  = s_bsp[b] - s_bs[b];
    int num  = s_cnt[b], nump = s_cp[b];
    int r    = num % G;
    int tail_start = (num != nump) ? (s_bsp[b+1] - G + r) : s_bsp[b+1];
    int v;
    if (j < tail_start)       v = j - off;
    else if (nump != G)       v = j - G - off;
    else { int tt = j - tail_start; int m = num > 0 ? num : 1; v = s_bs[b] + tt % m; }
    out[j] = v;
}

// ---------------- K5: per-bucket LDS bitmap rank + scatter ----------------
__global__ void rank_kernel(const uint2* __restrict__ rec,
                            const unsigned* __restrict__ recStart, int N,
                            int* __restrict__ xmap, int* __restrict__ ymap) {
    int b = blockIdx.x;                      // 0..NB2-1
    unsigned start = recStart[b], end = recStart[b+1];
    int map = (b >= NBUK);
    __shared__ unsigned bits[B_WORDS];
    __shared__ unsigned pref[B_WORDS];
    __shared__ unsigned sc[256];
    int t = threadIdx.x;
    #pragma unroll
    for (int k = 0; k < B_WORDS/256; k++) bits[t + 256*k] = 0;
    __syncthreads();
    for (unsigned i = start + t; i < end; i += 256) {
        unsigned key = rec[i].x;
        unsigned local = key & 131071u;
        atomicOr(&bits[local >> 5], 1u << (local & 31));
    }
    __syncthreads();
    unsigned base = t * 16;
    unsigned w[16];
    unsigned s = 0;
    #pragma unroll
    for (int k = 0; k < 16; k++) { w[k] = bits[base + k]; s += __popc(w[k]); }
    sc[t] = s; __syncthreads();
    for (int d = 1; d < 256; d <<= 1) {
        unsigned u = (t >= d) ? sc[t - d] : 0;
        __syncthreads();
        sc[t] += u;
        __syncthreads();
    }
    unsigned excl = sc[t] - s;
    #pragma unroll
    for (int k = 0; k < 16; k++) { pref[base + k] = excl; excl += __popc(w[k]); }
    __syncthreads();
    int* out = map ? ymap : xmap;
    unsigned rankBase = start - (map ? (unsigned)N : 0u);
    for (unsigned i = start + t; i < end; i += 256) {
        uint2 r = rec[i];
        unsigned local = r.x & 131071u;
        unsigned wd = local >> 5, bt = local & 31;
        unsigned rank = rankBase + pref[wd] + __popc(bits[wd] & ((1u << bt) - 1u));
        out[rank] = (int)r.y;
    }
}

// ---------------- launch ----------------
extern "C" void kernel_launch(void* const* d_in, const int* in_sizes, int n_in,
                              void* d_out, int out_size, void* d_ws, size_t ws_size,
                              hipStream_t stream) {
    const int* coords = (const int*)d_in[0];
    int N  = in_sizes[0] / 4;
    int Np = out_size - 3 * N;
    int chunk = (N + NBLK - 1) / NBLK;

    char* ws = (char*)d_ws;
    int*      ctrl     = (int*)(ws + 0);              // 256 B
    unsigned* totals   = (unsigned*)(ws + 256);       // 2178*4          -> ends 8968
    unsigned* recStart = (unsigned*)(ws + 8968);      // 2179*4          -> ends 17684
    unsigned* histMat  = (unsigned*)(ws + 17696);     // 256*2178*4 = 2,230,272 -> ends 2,247,968
    uint2*    rec      = (uint2*)(ws + 2247968);      // 2N*8 B (~32 MB)

    int* out  = (int*)d_out;
    int* f2w  = out;
    int* w2f  = out + Np;
    int* xmap = out + Np + N;
    int* ymap = out + Np + 2*N;

    hipMemsetAsync(ctrl, 0, 256, stream);

    hist_kernel<<<NBLK, 256, 0, stream>>>((const int4*)coords, N, chunk, ctrl, histMat);
    colscan_kernel<<<(NB2 + 255)/256, 256, 0, stream>>>(histMat, totals);
    scan_kernel<<<1, 256, 0, stream>>>(ctrl, totals, recStart);
    bin_kernel<<<NBLK, 256, 0, stream>>>((const int4*)coords, N, chunk, ctrl, recStart, histMat, rec, w2f);
    f2w_kernel<<<(Np + 255)/256, 256, 0, stream>>>(Np, ctrl, f2w);
    rank_kernel<<<NB2, 256, 0, stream>>>(rec, recStart, N, xmap, ymap);
}